// Round 2
// baseline (174.840 us; speedup 1.0000x reference)
//
#include <hip/hip_runtime.h>

#define ORDER 8
#define FDIM 4096
#define NROWS 8192
#define THREADS 256
#define RPB 4            // rows of x per block
#define F4T 4            // float4s per thread per row: 4096/4/256
#define F4DIM (FDIM/4)   // 1024 float4s per row
#define NPAIR 36         // upper-triangular pairs of 8

// ---------------------------------------------------------------------------
// Prep: reparameterize v, d, bias; normalize v rows.
// blocks 0..7 -> vn row b ; block 8 -> d ; block 9 -> bias
// ---------------------------------------------------------------------------
__global__ __launch_bounds__(THREADS) void obd_prep(
    const float* __restrict__ v_mean, const float* __restrict__ v_logvar,
    const float* __restrict__ eps_v,
    const float* __restrict__ d_mean, const float* __restrict__ d_logvar,
    const float* __restrict__ eps_d,
    const float* __restrict__ b_mean, const float* __restrict__ b_logvar,
    const float* __restrict__ eps_b,
    float* __restrict__ vn, float* __restrict__ dsc, float* __restrict__ bias)
{
    const int b = blockIdx.x;
    const int t = threadIdx.x;
    __shared__ float red[THREADS / 64];

    if (b < ORDER) {
        const float4* vm = (const float4*)(v_mean   + (size_t)b * FDIM);
        const float4* vl = (const float4*)(v_logvar + (size_t)b * FDIM);
        const float4* ev = (const float4*)(eps_v    + (size_t)b * FDIM);
        float4 val[F4T];
        float ss = 0.f;
        #pragma unroll
        for (int k = 0; k < F4T; ++k) {
            const int idx = t + k * THREADS;
            float4 m = vm[idx], l = vl[idx], e = ev[idx];
            float4 v;
            v.x = fmaf(expf(0.5f * l.x), e.x, m.x);
            v.y = fmaf(expf(0.5f * l.y), e.y, m.y);
            v.z = fmaf(expf(0.5f * l.z), e.z, m.z);
            v.w = fmaf(expf(0.5f * l.w), e.w, m.w);
            val[k] = v;
            ss += v.x * v.x + v.y * v.y + v.z * v.z + v.w * v.w;
        }
        #pragma unroll
        for (int off = 32; off; off >>= 1) ss += __shfl_down(ss, off);
        const int wave = t >> 6, lane = t & 63;
        if (lane == 0) red[wave] = ss;
        __syncthreads();
        const float inv = 1.0f / sqrtf(red[0] + red[1] + red[2] + red[3]);
        float4* vno = (float4*)(vn + (size_t)b * FDIM);
        #pragma unroll
        for (int k = 0; k < F4T; ++k) {
            const int idx = t + k * THREADS;
            float4 v = val[k];
            v.x *= inv; v.y *= inv; v.z *= inv; v.w *= inv;
            vno[idx] = v;
        }
    } else if (b == ORDER) {
        #pragma unroll
        for (int k = 0; k < 16; ++k) {
            const int idx = t + k * THREADS;
            dsc[idx] = fmaf(expf(0.5f * d_logvar[idx]), eps_d[idx], d_mean[idx]);
        }
    } else {
        #pragma unroll
        for (int k = 0; k < 16; ++k) {
            const int idx = t + k * THREADS;
            bias[idx] = fmaf(expf(0.5f * b_logvar[idx]), eps_b[idx], b_mean[idx]);
        }
    }
}

// ---------------------------------------------------------------------------
// Gram + T: single block. G[i][j] = vn_i . vn_j (i<=j); then the compact-WY
// triangular factor: T[0][0]=2; col j: T[i][j] = -2 * sum_{m<j} T[i][m]G[m][j],
// T[j][j]=2.  H0..H7 = I - V T V^T.
// ---------------------------------------------------------------------------
__global__ __launch_bounds__(THREADS) void obd_gramT(
    const float* __restrict__ vn, float* __restrict__ Tm)
{
    const int t = threadIdx.x;
    const int wave = t >> 6, lane = t & 63;
    const float4* Vv = (const float4*)vn;

    float acc[ORDER][ORDER];
    #pragma unroll
    for (int i = 0; i < ORDER; ++i)
        #pragma unroll
        for (int j = i; j < ORDER; ++j) acc[i][j] = 0.f;

    #pragma unroll
    for (int k = 0; k < F4T; ++k) {
        const int idx = t + k * THREADS;
        float4 vc[ORDER];
        #pragma unroll
        for (int i = 0; i < ORDER; ++i) vc[i] = Vv[i * F4DIM + idx];
        #pragma unroll
        for (int i = 0; i < ORDER; ++i)
            #pragma unroll
            for (int j = i; j < ORDER; ++j) {
                acc[i][j] = fmaf(vc[i].x, vc[j].x, acc[i][j]);
                acc[i][j] = fmaf(vc[i].y, vc[j].y, acc[i][j]);
                acc[i][j] = fmaf(vc[i].z, vc[j].z, acc[i][j]);
                acc[i][j] = fmaf(vc[i].w, vc[j].w, acc[i][j]);
            }
    }
    #pragma unroll
    for (int off = 32; off; off >>= 1)
        #pragma unroll
        for (int i = 0; i < ORDER; ++i)
            #pragma unroll
            for (int j = i; j < ORDER; ++j)
                acc[i][j] += __shfl_down(acc[i][j], off);

    __shared__ float red[THREADS / 64][NPAIR];
    if (lane == 0) {
        int p = 0;
        #pragma unroll
        for (int i = 0; i < ORDER; ++i)
            #pragma unroll
            for (int j = i; j < ORDER; ++j) red[wave][p++] = acc[i][j];
    }
    __syncthreads();
    if (t == 0) {
        float G[ORDER][ORDER];
        int p = 0;
        for (int i = 0; i < ORDER; ++i)
            for (int j = i; j < ORDER; ++j) {
                G[i][j] = red[0][p] + red[1][p] + red[2][p] + red[3][p];
                ++p;
            }
        float T[ORDER][ORDER];
        for (int i = 0; i < ORDER; ++i)
            for (int j = 0; j < ORDER; ++j) T[i][j] = 0.f;
        T[0][0] = 2.f;
        for (int j = 1; j < ORDER; ++j) {
            for (int i = 0; i < j; ++i) {
                float s = 0.f;
                for (int m = i; m < j; ++m) s += T[i][m] * G[m][j];
                T[i][j] = -2.f * s;
            }
            T[j][j] = 2.f;
        }
        for (int i = 0; i < ORDER; ++i)
            for (int j = 0; j < ORDER; ++j) Tm[i * ORDER + j] = T[i][j];
    }
}

// ---------------------------------------------------------------------------
// Main (compact WY): per block, 4 rows in registers.
//   pass 1: p[rr][i] = row_rr . v_i      (all 8 dots, one sweep, one barrier)
//   q = p @ T  (8x8 upper-tri, from LDS)
//   pass 2: row -= sum_j q[j] v_j ; fused out = row*d + bias
// ---------------------------------------------------------------------------
__global__ __launch_bounds__(THREADS, 4) void obd_wy(
    const float* __restrict__ x, const float* __restrict__ vn,
    const float* __restrict__ Tm, const float* __restrict__ dsc,
    const float* __restrict__ bias, float* __restrict__ out)
{
    const int t = threadIdx.x;
    const int wave = t >> 6, lane = t & 63;
    const size_t row0 = (size_t)blockIdx.x * RPB;
    const float4* xv = (const float4*)x;
    const float4* Vv = (const float4*)vn;
    float4* ov = (float4*)out;

    __shared__ float Ts[64];
    __shared__ float red[THREADS / 64][RPB * ORDER];
    if (t < 64) Ts[t] = Tm[t];

    // Load 4 rows into registers.
    float4 r[RPB][F4T];
    #pragma unroll
    for (int rr = 0; rr < RPB; ++rr) {
        const size_t base = (row0 + rr) * F4DIM;
        #pragma unroll
        for (int k = 0; k < F4T; ++k)
            r[rr][k] = xv[base + t + k * THREADS];
    }

    // Pass 1: all 8 dots at once.
    float p[RPB][ORDER];
    #pragma unroll
    for (int rr = 0; rr < RPB; ++rr)
        #pragma unroll
        for (int i = 0; i < ORDER; ++i) p[rr][i] = 0.f;

    #pragma unroll
    for (int k = 0; k < F4T; ++k) {
        const int idx = t + k * THREADS;
        #pragma unroll
        for (int i = 0; i < ORDER; ++i) {
            const float4 vc = Vv[i * F4DIM + idx];
            #pragma unroll
            for (int rr = 0; rr < RPB; ++rr) {
                p[rr][i] = fmaf(r[rr][k].x, vc.x, p[rr][i]);
                p[rr][i] = fmaf(r[rr][k].y, vc.y, p[rr][i]);
                p[rr][i] = fmaf(r[rr][k].z, vc.z, p[rr][i]);
                p[rr][i] = fmaf(r[rr][k].w, vc.w, p[rr][i]);
            }
        }
    }
    #pragma unroll
    for (int off = 32; off; off >>= 1)
        #pragma unroll
        for (int rr = 0; rr < RPB; ++rr)
            #pragma unroll
            for (int i = 0; i < ORDER; ++i)
                p[rr][i] += __shfl_down(p[rr][i], off);
    if (lane == 0) {
        #pragma unroll
        for (int rr = 0; rr < RPB; ++rr)
            #pragma unroll
            for (int i = 0; i < ORDER; ++i)
                red[wave][rr * ORDER + i] = p[rr][i];
    }
    __syncthreads();  // also covers the Ts staging load

    // q = p @ T  (negated for the fma update)
    float mq[RPB][ORDER];
    #pragma unroll
    for (int rr = 0; rr < RPB; ++rr) {
        float dot[ORDER];
        #pragma unroll
        for (int i = 0; i < ORDER; ++i)
            dot[i] = red[0][rr * ORDER + i] + red[1][rr * ORDER + i]
                   + red[2][rr * ORDER + i] + red[3][rr * ORDER + i];
        #pragma unroll
        for (int j = 0; j < ORDER; ++j) {
            float s = 0.f;
            #pragma unroll
            for (int i = 0; i <= j; ++i) s = fmaf(dot[i], Ts[i * ORDER + j], s);
            mq[rr][j] = -s;
        }
    }

    // Pass 2: rank-8 update + fused epilogue.
    const float4* dv = (const float4*)dsc;
    const float4* bv = (const float4*)bias;
    #pragma unroll
    for (int k = 0; k < F4T; ++k) {
        const int idx = t + k * THREADS;
        #pragma unroll
        for (int i = 0; i < ORDER; ++i) {
            const float4 vc = Vv[i * F4DIM + idx];
            #pragma unroll
            for (int rr = 0; rr < RPB; ++rr) {
                r[rr][k].x = fmaf(mq[rr][i], vc.x, r[rr][k].x);
                r[rr][k].y = fmaf(mq[rr][i], vc.y, r[rr][k].y);
                r[rr][k].z = fmaf(mq[rr][i], vc.z, r[rr][k].z);
                r[rr][k].w = fmaf(mq[rr][i], vc.w, r[rr][k].w);
            }
        }
        const float4 dd = dv[idx];
        const float4 bb = bv[idx];
        #pragma unroll
        for (int rr = 0; rr < RPB; ++rr) {
            float4 o;
            o.x = fmaf(r[rr][k].x, dd.x, bb.x);
            o.y = fmaf(r[rr][k].y, dd.y, bb.y);
            o.z = fmaf(r[rr][k].z, dd.z, bb.z);
            o.w = fmaf(r[rr][k].w, dd.w, bb.w);
            ov[(row0 + rr) * F4DIM + idx] = o;
        }
    }
}

extern "C" void kernel_launch(void* const* d_in, const int* in_sizes, int n_in,
                              void* d_out, int out_size, void* d_ws, size_t ws_size,
                              hipStream_t stream) {
    const float* x        = (const float*)d_in[0];
    const float* v_mean   = (const float*)d_in[1];
    const float* v_logvar = (const float*)d_in[2];
    const float* d_mean   = (const float*)d_in[3];
    const float* d_logvar = (const float*)d_in[4];
    const float* b_mean   = (const float*)d_in[5];
    const float* b_logvar = (const float*)d_in[6];
    const float* eps_v    = (const float*)d_in[7];
    const float* eps_d    = (const float*)d_in[8];
    const float* eps_b    = (const float*)d_in[9];

    float* ws   = (float*)d_ws;
    float* vn   = ws;                                  // 8*4096
    float* dsc  = ws + ORDER * FDIM;                   // 4096
    float* bias = ws + ORDER * FDIM + FDIM;            // 4096
    float* Tm   = ws + ORDER * FDIM + 2 * FDIM;        // 64

    obd_prep<<<ORDER + 2, THREADS, 0, stream>>>(
        v_mean, v_logvar, eps_v, d_mean, d_logvar, eps_d,
        b_mean, b_logvar, eps_b, vn, dsc, bias);
    obd_gramT<<<1, THREADS, 0, stream>>>(vn, Tm);
    obd_wy<<<NROWS / RPB, THREADS, 0, stream>>>(
        x, vn, Tm, dsc, bias, (float*)d_out);
}

// Round 3
// 76.077 us; speedup vs baseline: 2.2982x; 2.2982x over previous
//
#include <hip/hip_runtime.h>

#define ORDER 8
#define FDIM 4096
#define NROWS 8192
#define THREADS 256
#define RPB 4            // rows of x per block
#define F4T 4            // float4s per thread per row: 4096/4/256
#define F4DIM (FDIM/4)   // 1024 float4s per row
#define NPAIR 36         // upper-triangular pairs of 8

// ---------------------------------------------------------------------------
// Prep: reparameterize v, d, bias; normalize v rows.
// blocks 0..7 -> vn row b ; block 8 -> d ; block 9 -> bias
// ---------------------------------------------------------------------------
__global__ __launch_bounds__(THREADS) void obd_prep(
    const float* __restrict__ v_mean, const float* __restrict__ v_logvar,
    const float* __restrict__ eps_v,
    const float* __restrict__ d_mean, const float* __restrict__ d_logvar,
    const float* __restrict__ eps_d,
    const float* __restrict__ b_mean, const float* __restrict__ b_logvar,
    const float* __restrict__ eps_b,
    float* __restrict__ vn, float* __restrict__ dsc, float* __restrict__ bias)
{
    const int b = blockIdx.x;
    const int t = threadIdx.x;
    __shared__ float red[THREADS / 64];

    if (b < ORDER) {
        const float4* vm = (const float4*)(v_mean   + (size_t)b * FDIM);
        const float4* vl = (const float4*)(v_logvar + (size_t)b * FDIM);
        const float4* ev = (const float4*)(eps_v    + (size_t)b * FDIM);
        float4 val[F4T];
        float ss = 0.f;
        #pragma unroll
        for (int k = 0; k < F4T; ++k) {
            const int idx = t + k * THREADS;
            float4 m = vm[idx], l = vl[idx], e = ev[idx];
            float4 v;
            v.x = fmaf(expf(0.5f * l.x), e.x, m.x);
            v.y = fmaf(expf(0.5f * l.y), e.y, m.y);
            v.z = fmaf(expf(0.5f * l.z), e.z, m.z);
            v.w = fmaf(expf(0.5f * l.w), e.w, m.w);
            val[k] = v;
            ss += v.x * v.x + v.y * v.y + v.z * v.z + v.w * v.w;
        }
        #pragma unroll
        for (int off = 32; off; off >>= 1) ss += __shfl_down(ss, off);
        const int wave = t >> 6, lane = t & 63;
        if (lane == 0) red[wave] = ss;
        __syncthreads();
        const float inv = 1.0f / sqrtf(red[0] + red[1] + red[2] + red[3]);
        float4* vno = (float4*)(vn + (size_t)b * FDIM);
        #pragma unroll
        for (int k = 0; k < F4T; ++k) {
            const int idx = t + k * THREADS;
            float4 v = val[k];
            v.x *= inv; v.y *= inv; v.z *= inv; v.w *= inv;
            vno[idx] = v;
        }
    } else if (b == ORDER) {
        #pragma unroll
        for (int k = 0; k < 16; ++k) {
            const int idx = t + k * THREADS;
            dsc[idx] = fmaf(expf(0.5f * d_logvar[idx]), eps_d[idx], d_mean[idx]);
        }
    } else {
        #pragma unroll
        for (int k = 0; k < 16; ++k) {
            const int idx = t + k * THREADS;
            bias[idx] = fmaf(expf(0.5f * b_logvar[idx]), eps_b[idx], b_mean[idx]);
        }
    }
}

// ---------------------------------------------------------------------------
// Gram + T: single block. G[i][j] = vn_i . vn_j (i<=j); then the compact-WY
// triangular factor: T[0][0]=2; col j: T[i][j] = -2 * sum_{m<j} T[i][m]G[m][j],
// T[j][j]=2.  H0..H7 = I - V T V^T.
// ---------------------------------------------------------------------------
__global__ __launch_bounds__(THREADS) void obd_gramT(
    const float* __restrict__ vn, float* __restrict__ Tm)
{
    const int t = threadIdx.x;
    const int wave = t >> 6, lane = t & 63;
    const float4* Vv = (const float4*)vn;

    float acc[ORDER][ORDER];
    #pragma unroll
    for (int i = 0; i < ORDER; ++i)
        #pragma unroll
        for (int j = i; j < ORDER; ++j) acc[i][j] = 0.f;

    #pragma unroll
    for (int k = 0; k < F4T; ++k) {
        const int idx = t + k * THREADS;
        float4 vc[ORDER];
        #pragma unroll
        for (int i = 0; i < ORDER; ++i) vc[i] = Vv[i * F4DIM + idx];
        #pragma unroll
        for (int i = 0; i < ORDER; ++i)
            #pragma unroll
            for (int j = i; j < ORDER; ++j) {
                acc[i][j] = fmaf(vc[i].x, vc[j].x, acc[i][j]);
                acc[i][j] = fmaf(vc[i].y, vc[j].y, acc[i][j]);
                acc[i][j] = fmaf(vc[i].z, vc[j].z, acc[i][j]);
                acc[i][j] = fmaf(vc[i].w, vc[j].w, acc[i][j]);
            }
    }
    #pragma unroll
    for (int off = 32; off; off >>= 1)
        #pragma unroll
        for (int i = 0; i < ORDER; ++i)
            #pragma unroll
            for (int j = i; j < ORDER; ++j)
                acc[i][j] += __shfl_down(acc[i][j], off);

    __shared__ float red[THREADS / 64][NPAIR];
    if (lane == 0) {
        int p = 0;
        #pragma unroll
        for (int i = 0; i < ORDER; ++i)
            #pragma unroll
            for (int j = i; j < ORDER; ++j) red[wave][p++] = acc[i][j];
    }
    __syncthreads();
    if (t == 0) {
        float G[ORDER][ORDER];
        int p = 0;
        for (int i = 0; i < ORDER; ++i)
            for (int j = i; j < ORDER; ++j) {
                G[i][j] = red[0][p] + red[1][p] + red[2][p] + red[3][p];
                ++p;
            }
        float T[ORDER][ORDER];
        for (int i = 0; i < ORDER; ++i)
            for (int j = 0; j < ORDER; ++j) T[i][j] = 0.f;
        T[0][0] = 2.f;
        for (int j = 1; j < ORDER; ++j) {
            for (int i = 0; i < j; ++i) {
                float s = 0.f;
                for (int m = i; m < j; ++m) s += T[i][m] * G[m][j];
                T[i][j] = -2.f * s;
            }
            T[j][j] = 2.f;
        }
        for (int i = 0; i < ORDER; ++i)
            for (int j = 0; j < ORDER; ++j) Tm[i * ORDER + j] = T[i][j];
    }
}

// ---------------------------------------------------------------------------
// Main (compact WY): per block, 4 rows in registers.
//   pass 1: p[rr][i] = row_rr . v_i      (all 8 dots, one sweep, one barrier)
//   q = p @ T  (8x8 upper-tri, from LDS)
//   pass 2: row -= sum_j q[j] v_j ; fused out = row*d + bias
// launch_bounds min-waves=2 -> VGPR cap 256: room for ~125 live regs, NO SPILL
// (R2's ",4" capped at 64 VGPR and spilled ~310 MB of scratch traffic).
// ---------------------------------------------------------------------------
__global__ __launch_bounds__(THREADS, 2) void obd_wy(
    const float* __restrict__ x, const float* __restrict__ vn,
    const float* __restrict__ Tm, const float* __restrict__ dsc,
    const float* __restrict__ bias, float* __restrict__ out)
{
    const int t = threadIdx.x;
    const int wave = t >> 6, lane = t & 63;
    const size_t row0 = (size_t)blockIdx.x * RPB;
    const float4* xv = (const float4*)x;
    const float4* Vv = (const float4*)vn;
    float4* ov = (float4*)out;

    __shared__ float Ts[64];
    __shared__ float red[THREADS / 64][RPB * ORDER];
    if (t < 64) Ts[t] = Tm[t];

    // Load 4 rows into registers.
    float4 r[RPB][F4T];
    #pragma unroll
    for (int rr = 0; rr < RPB; ++rr) {
        const size_t base = (row0 + rr) * F4DIM;
        #pragma unroll
        for (int k = 0; k < F4T; ++k)
            r[rr][k] = xv[base + t + k * THREADS];
    }

    // Pass 1: all 8 dots at once.
    float p[RPB][ORDER];
    #pragma unroll
    for (int rr = 0; rr < RPB; ++rr)
        #pragma unroll
        for (int i = 0; i < ORDER; ++i) p[rr][i] = 0.f;

    #pragma unroll
    for (int k = 0; k < F4T; ++k) {
        const int idx = t + k * THREADS;
        #pragma unroll
        for (int i = 0; i < ORDER; ++i) {
            const float4 vc = Vv[i * F4DIM + idx];
            #pragma unroll
            for (int rr = 0; rr < RPB; ++rr) {
                p[rr][i] = fmaf(r[rr][k].x, vc.x, p[rr][i]);
                p[rr][i] = fmaf(r[rr][k].y, vc.y, p[rr][i]);
                p[rr][i] = fmaf(r[rr][k].z, vc.z, p[rr][i]);
                p[rr][i] = fmaf(r[rr][k].w, vc.w, p[rr][i]);
            }
        }
    }
    #pragma unroll
    for (int off = 32; off; off >>= 1)
        #pragma unroll
        for (int rr = 0; rr < RPB; ++rr)
            #pragma unroll
            for (int i = 0; i < ORDER; ++i)
                p[rr][i] += __shfl_down(p[rr][i], off);
    if (lane == 0) {
        #pragma unroll
        for (int rr = 0; rr < RPB; ++rr)
            #pragma unroll
            for (int i = 0; i < ORDER; ++i)
                red[wave][rr * ORDER + i] = p[rr][i];
    }
    __syncthreads();  // also covers the Ts staging load

    // q = p @ T  (negated for the fma update)
    float mq[RPB][ORDER];
    #pragma unroll
    for (int rr = 0; rr < RPB; ++rr) {
        float dot[ORDER];
        #pragma unroll
        for (int i = 0; i < ORDER; ++i)
            dot[i] = red[0][rr * ORDER + i] + red[1][rr * ORDER + i]
                   + red[2][rr * ORDER + i] + red[3][rr * ORDER + i];
        #pragma unroll
        for (int j = 0; j < ORDER; ++j) {
            float s = 0.f;
            #pragma unroll
            for (int i = 0; i <= j; ++i) s = fmaf(dot[i], Ts[i * ORDER + j], s);
            mq[rr][j] = -s;
        }
    }

    // Pass 2: rank-8 update + fused epilogue.
    const float4* dv = (const float4*)dsc;
    const float4* bv = (const float4*)bias;
    #pragma unroll
    for (int k = 0; k < F4T; ++k) {
        const int idx = t + k * THREADS;
        #pragma unroll
        for (int i = 0; i < ORDER; ++i) {
            const float4 vc = Vv[i * F4DIM + idx];
            #pragma unroll
            for (int rr = 0; rr < RPB; ++rr) {
                r[rr][k].x = fmaf(mq[rr][i], vc.x, r[rr][k].x);
                r[rr][k].y = fmaf(mq[rr][i], vc.y, r[rr][k].y);
                r[rr][k].z = fmaf(mq[rr][i], vc.z, r[rr][k].z);
                r[rr][k].w = fmaf(mq[rr][i], vc.w, r[rr][k].w);
            }
        }
        const float4 dd = dv[idx];
        const float4 bb = bv[idx];
        #pragma unroll
        for (int rr = 0; rr < RPB; ++rr) {
            float4 o;
            o.x = fmaf(r[rr][k].x, dd.x, bb.x);
            o.y = fmaf(r[rr][k].y, dd.y, bb.y);
            o.z = fmaf(r[rr][k].z, dd.z, bb.z);
            o.w = fmaf(r[rr][k].w, dd.w, bb.w);
            ov[(row0 + rr) * F4DIM + idx] = o;
        }
    }
}

extern "C" void kernel_launch(void* const* d_in, const int* in_sizes, int n_in,
                              void* d_out, int out_size, void* d_ws, size_t ws_size,
                              hipStream_t stream) {
    const float* x        = (const float*)d_in[0];
    const float* v_mean   = (const float*)d_in[1];
    const float* v_logvar = (const float*)d_in[2];
    const float* d_mean   = (const float*)d_in[3];
    const float* d_logvar = (const float*)d_in[4];
    const float* b_mean   = (const float*)d_in[5];
    const float* b_logvar = (const float*)d_in[6];
    const float* eps_v    = (const float*)d_in[7];
    const float* eps_d    = (const float*)d_in[8];
    const float* eps_b    = (const float*)d_in[9];

    float* ws   = (float*)d_ws;
    float* vn   = ws;                                  // 8*4096
    float* dsc  = ws + ORDER * FDIM;                   // 4096
    float* bias = ws + ORDER * FDIM + FDIM;            // 4096
    float* Tm   = ws + ORDER * FDIM + 2 * FDIM;        // 64

    obd_prep<<<ORDER + 2, THREADS, 0, stream>>>(
        v_mean, v_logvar, eps_v, d_mean, d_logvar, eps_d,
        b_mean, b_logvar, eps_b, vn, dsc, bias);
    obd_gramT<<<1, THREADS, 0, stream>>>(vn, Tm);
    obd_wy<<<NROWS / RPB, THREADS, 0, stream>>>(
        x, vn, Tm, dsc, bias, (float*)d_out);
}